// Round 4
// baseline (3074.368 us; speedup 1.0000x reference)
//
#include <hip/hip_runtime.h>
#include <stdint.h>

typedef short bf16x8 __attribute__((ext_vector_type(8)));
typedef _Float16 f16x8 __attribute__((ext_vector_type(8)));
typedef float f32x4 __attribute__((ext_vector_type(4)));
typedef unsigned int u32x2_t __attribute__((ext_vector_type(2)));
typedef unsigned int u32x4_t __attribute__((ext_vector_type(4)));
typedef unsigned int u32;
typedef unsigned short u16;
typedef unsigned char u8;
typedef unsigned long long u64;

#define NB  16
#define SEQ 2048
#define DD  1024
#define BM  64          // a-rows per WG (main path)
#define KVB 32
#define NKB (SEQ / KVB)

// d_ws layout (bytes)
#define WS_QTI 0ULL            // [b][d][1024 u32]  pair-interleaved Qhi^T : 64 MB
#define WS_QHI (64ULL << 20)   // [b][kv][d] f16 hi : 64 MB
#define WS_QLO (128ULL << 20)  // [b][kv][d] f16 lo : 64 MB
#define WS_Q8  (192ULL << 20)  // [b][kv][d] fp8 e4m3 of q : 32 MB
#define WS_NEED (224ULL << 20)

union HF { u32 u[4]; u32x4_t u4; f16x8 v; };

__device__ __forceinline__ f32x4 z4() {
  f32x4 v; v[0] = 0.f; v[1] = 0.f; v[2] = 0.f; v[3] = 0.f; return v;
}
__device__ __forceinline__ float h16(float x) {
  // round-to-nearest f16-representable value, kept in f32
  return __uint_as_float((__float_as_uint(x) + 0x1000u) & 0xFFFFE000u);
}
__device__ __forceinline__ u32 packh(float a, float b) {
  auto t = __builtin_amdgcn_cvt_pkrtz(a, b);   // __fp16x2, bit-cast to u32
  return *(u32*)&t;
}
__device__ __forceinline__ f32x4 mfma16(f16x8 a, f16x8 b, f32x4 c) {
  return __builtin_amdgcn_mfma_f32_16x16x32_f16(a, b, c, 0, 0, 0);
}
__device__ __forceinline__ f32x4 mfma8(u64 a, u64 b, f32x4 c) {
  return __builtin_amdgcn_mfma_f32_16x16x32_fp8_bf8((long)a, (long)b, c, 0, 0, 0);
}

// ---------------- prepass: q -> Qhi / Qlo / Q8 / QTI ----------------
__global__ __launch_bounds__(256)
void prepass(const float* __restrict__ Q, u32* __restrict__ QTI,
             u16* __restrict__ Qhi, u16* __restrict__ Qlo, u8* __restrict__ Q8) {
  __shared__ u16 hl[32][72];
  const int t = threadIdx.x;
  const int bidx = (int)blockIdx.x;          // b*1024 + kvb*16 + db
  const int db = bidx & 15, kvb = (bidx >> 4) & 63, b = bidx >> 10;
  const int r = t >> 3, dc = (t & 7) * 8;
  const int kv = kvb * 32 + r;
  const size_t row = (size_t)(b * SEQ + kv) * DD + db * 64 + dc;
  f32x4 v0 = ((const f32x4*)(Q + row))[0];
  f32x4 v1 = ((const f32x4*)(Q + row))[1];
  float e[8] = { v0[0], v0[1], v0[2], v0[3], v1[0], v1[1], v1[2], v1[3] };
  float hh[8], ll[8];
#pragma unroll
  for (int i = 0; i < 8; ++i) { hh[i] = h16(e[i]); ll[i] = e[i] - hh[i]; }
  u32x4_t hw, lw;
#pragma unroll
  for (int j = 0; j < 4; ++j) {
    hw[j] = packh(hh[2 * j], hh[2 * j + 1]);
    lw[j] = packh(ll[2 * j], ll[2 * j + 1]);
  }
  *(u32x4_t*)(Qhi + row) = hw;
  *(u32x4_t*)(Qlo + row) = lw;
  u32 c0 = __builtin_amdgcn_cvt_pk_fp8_f32(e[0], e[1], 0, 0);
  c0 = __builtin_amdgcn_cvt_pk_fp8_f32(e[2], e[3], c0, 1);
  u32 c1 = __builtin_amdgcn_cvt_pk_fp8_f32(e[4], e[5], 0, 0);
  c1 = __builtin_amdgcn_cvt_pk_fp8_f32(e[6], e[7], c1, 1);
  u32x2_t c2; c2[0] = c0; c2[1] = c1;
  *(u32x2_t*)(Q8 + row) = c2;
  // stage f16-hi bits for the transposed-interleaved write
#pragma unroll
  for (int j = 0; j < 4; ++j) {
    hl[r][dc + 2 * j]     = (u16)(hw[j] & 0xffffu);
    hl[r][dc + 2 * j + 1] = (u16)(hw[j] >> 16);
  }
  __syncthreads();
  const int d = t >> 2, i4 = (t & 3) * 4;
  u32x4_t w;
#pragma unroll
  for (int ii = 0; ii < 4; ++ii) {
    const int i = i4 + ii;
    w[ii] = (u32)hl[i][d] | ((u32)hl[i + 16][d] << 16);  // (kv0+i, kv0+16+i)
  }
  u32* dst = QTI + ((size_t)(b * DD + db * 64 + d)) * 1024 + kvb * 16 + i4;
  *(u32x4_t*)dst = w;
}

// ---------------- main fused kernel ----------------
__global__ __launch_bounds__(1024, 4)
void attn_main(const float* __restrict__ Ag, const u32* __restrict__ QTI,
               const u16* __restrict__ Qhi, const u16* __restrict__ Qlo,
               const u8* __restrict__ Q8, float* __restrict__ Og) {
  __shared__ float sp[2][8][32][36];          // per-wave partial S^T   (73728 B)
  __shared__ float ssum[2][32][36];           // reduced S^T per group  ( 9216 B)
  __shared__ __align__(16) u8 aloB[16][4096]; // A-lo bf8, swizzled     (65536 B)

  const int tid  = (int)threadIdx.x;
  const int w    = tid >> 6;
  const int lane = tid & 63;
  const int g    = lane >> 4;
  const int m    = lane & 15;
  const int rg   = w >> 3;      // row-group (0,1): a-rows rg*32..rg*32+31
  const int wd   = w & 7;       // d-chunk
  const int dw   = wd * 128;

  // XCD chunk swizzle: 512 = 8 * 64; each XCD round covers one batch
  const int p = (int)blockIdx.x;
  const int l = (p & 7) * 64 + (p >> 3);
  const int b = l >> 5;
  const int ablk = l & 31;

  const float* Abase = Ag + ((size_t)(b * SEQ + ablk * BM + rg * 32)) * DD;
  float*       Ob    = Og + ((size_t)(b * SEQ + ablk * BM + rg * 32)) * DD;

  // ---- prologue: A-tile -> f16-hi frags (regs) + bf8-lo (LDS, swizzled)
  f16x8 ah[2][4];
#pragma unroll
  for (int rt = 0; rt < 2; ++rt) {
#pragma unroll
    for (int kt = 0; kt < 4; ++kt) {
      const float* src = Abase + (size_t)(rt * 16 + m) * DD + dw + kt * 32 + g * 8;
      f32x4 v0 = ((const f32x4*)src)[0];
      f32x4 v1 = ((const f32x4*)src)[1];
      float e[8] = { v0[0], v0[1], v0[2], v0[3], v1[0], v1[1], v1[2], v1[3] };
      float hh[8], ll[8];
#pragma unroll
      for (int i = 0; i < 8; ++i) { hh[i] = h16(e[i]); ll[i] = e[i] - hh[i]; }
      HF fh;
#pragma unroll
      for (int j = 0; j < 4; ++j) fh.u[j] = packh(hh[2 * j], hh[2 * j + 1]);
      ah[rt][kt] = fh.v;
      u32 c0 = __builtin_amdgcn_cvt_pk_bf8_f32(ll[0], ll[1], 0, 0);
      c0 = __builtin_amdgcn_cvt_pk_bf8_f32(ll[2], ll[3], c0, 1);
      u32 c1 = __builtin_amdgcn_cvt_pk_bf8_f32(ll[4], ll[5], 0, 0);
      c1 = __builtin_amdgcn_cvt_pk_bf8_f32(ll[6], ll[7], c1, 1);
      const u32 off = (u32)(((rt * 16 + m) * 128 + kt * 32 + g * 8) ^ ((m & 7) << 3));
      *(u64*)(&aloB[w][off]) = (u64)c0 | ((u64)c1 << 32);
    }
  }

  f32x4 oacc[2][8];
#pragma unroll
  for (int mt = 0; mt < 2; ++mt)
#pragma unroll
    for (int nt = 0; nt < 8; ++nt) oacc[mt][nt] = z4();

  float M0 = -1e30f, M1 = -1e30f, L0 = 0.f, L1 = 0.f;

#pragma unroll 1
  for (int kb = 0; kb < NKB; ++kb) {
    const int kv0 = kb * KVB;

    // ---- S^T partial (3 MFMA terms: AhQh + AhQl + Alo8*Q8), ct-sequential
#pragma unroll
    for (int ct = 0; ct < 2; ++ct) {
      f32x4 s0 = z4(), s1 = z4();
      const size_t qrow = (size_t)(b * SEQ + kv0 + ct * 16 + m) * DD + dw + g * 8;
      const u16* ph = Qhi + qrow;
      const u16* pl = Qlo + qrow;
      const u8*  p8 = Q8  + qrow;
#pragma unroll
      for (int kt = 0; kt < 4; ++kt) {
        HF qh, ql;
        qh.u4 = *(const u32x4_t*)(ph + kt * 32);
        ql.u4 = *(const u32x4_t*)(pl + kt * 32);
        const u64 q8v = *(const u64*)(p8 + kt * 32);
        const u64 a0 = *(const u64*)(&aloB[w][(u32)(((m) * 128 + kt * 32 + g * 8) ^ ((m & 7) << 3))]);
        const u64 a1 = *(const u64*)(&aloB[w][(u32)(((16 + m) * 128 + kt * 32 + g * 8) ^ ((m & 7) << 3))]);
        s0 = mfma16(qh.v, ah[0][kt], s0);
        s0 = mfma16(ql.v, ah[0][kt], s0);
        s0 = mfma8(q8v, a0, s0);
        s1 = mfma16(qh.v, ah[1][kt], s1);
        s1 = mfma16(ql.v, ah[1][kt], s1);
        s1 = mfma8(q8v, a1, s1);
      }
      *(f32x4*)&sp[rg][wd][m][ct * 16 + g * 4]      = s0;
      *(f32x4*)&sp[rg][wd][16 + m][ct * 16 + g * 4] = s1;
    }
    __syncthreads();

    // ---- cross-wave reduce (1024 threads x 2 groups)
    {
      const int r = tid >> 5, c = tid & 31;
#pragma unroll
      for (int grp = 0; grp < 2; ++grp) {
        float acc = sp[grp][0][r][c];
#pragma unroll
        for (int ww = 1; ww < 8; ++ww) acc += sp[grp][ww][r][c];
        ssum[grp][r][c] = acc;
      }
    }
    __syncthreads();

    // ---- full S^T back in C-fragment layout; online softmax (per row-group)
    f32x4 sv[2][2];
#pragma unroll
    for (int ct = 0; ct < 2; ++ct)
#pragma unroll
      for (int rt = 0; rt < 2; ++rt)
        sv[ct][rt] = *(const f32x4*)&ssum[rg][rt * 16 + m][ct * 16 + g * 4];

    float mx0 = -1e30f, mx1 = -1e30f;
#pragma unroll
    for (int ct = 0; ct < 2; ++ct)
#pragma unroll
      for (int j = 0; j < 4; ++j) {
        mx0 = fmaxf(mx0, sv[ct][0][j]);
        mx1 = fmaxf(mx1, sv[ct][1][j]);
      }
    mx0 = fmaxf(mx0, __shfl_xor(mx0, 16));
    mx0 = fmaxf(mx0, __shfl_xor(mx0, 32));
    mx1 = fmaxf(mx1, __shfl_xor(mx1, 16));
    mx1 = fmaxf(mx1, __shfl_xor(mx1, 32));

    if (__any((mx0 > M0) | (mx1 > M1))) {
      const float nM0 = fmaxf(M0, mx0), nM1 = fmaxf(M1, mx1);
      const float c0 = __expf(M0 - nM0), c1 = __expf(M1 - nM1);
      M0 = nM0; M1 = nM1;
      L0 *= c0; L1 *= c1;
      f32x4 cr0, cr1;
#pragma unroll
      for (int j = 0; j < 4; ++j) {
        cr0[j] = __shfl(c0, g * 4 + j);
        cr1[j] = __shfl(c1, g * 4 + j);
      }
#pragma unroll
      for (int nt = 0; nt < 8; ++nt)
#pragma unroll
        for (int j = 0; j < 4; ++j) {
          oacc[0][nt][j] *= cr0[j];
          oacc[1][nt][j] *= cr1[j];
        }
    }

    f32x4 p00, p10, p01, p11;   // [ct][row-half]
#pragma unroll
    for (int j = 0; j < 4; ++j) {
      p00[j] = __expf(sv[0][0][j] - M0);
      p10[j] = __expf(sv[1][0][j] - M0);
      p01[j] = __expf(sv[0][1][j] - M1);
      p11[j] = __expf(sv[1][1][j] - M1);
    }
    float rs0 = 0.f, rs1 = 0.f;
#pragma unroll
    for (int j = 0; j < 4; ++j) {
      rs0 += p00[j] + p10[j];
      rs1 += p01[j] + p11[j];
    }
    rs0 += __shfl_xor(rs0, 16); rs0 += __shfl_xor(rs0, 32);
    rs1 += __shfl_xor(rs1, 16); rs1 += __shfl_xor(rs1, 32);
    L0 += rs0; L1 += rs1;

    HF pa0, pa1;  // u[j]: lo=kv0+g*4+j, hi=kv0+16+g*4+j  (matches QTI words)
#pragma unroll
    for (int j = 0; j < 4; ++j) {
      pa0.u[j] = packh(p00[j], p10[j]);
      pa1.u[j] = packh(p01[j], p11[j]);
    }

    // ---- PV: A = P (regs, f16), B = V from QTI (global, L2-resident)
    const u32* vrow = QTI + ((size_t)(b * DD + dw + m)) * 1024 + kb * 16 + g * 4;
#pragma unroll
    for (int nt = 0; nt < 8; ++nt) {
      HF bq;
      bq.u4 = *(const u32x4_t*)(vrow + (size_t)nt * 16 * 1024);
      oacc[0][nt] = mfma16(pa0.v, bq.v, oacc[0][nt]);
      oacc[1][nt] = mfma16(pa1.v, bq.v, oacc[1][nt]);
    }
  }

  // ---- epilogue: normalize by L and store
  f32x4 i0, i1;
#pragma unroll
  for (int j = 0; j < 4; ++j) {
    i0[j] = 1.f / __shfl(L0, g * 4 + j);
    i1[j] = 1.f / __shfl(L1, g * 4 + j);
  }
#pragma unroll
  for (int mt = 0; mt < 2; ++mt)
#pragma unroll
    for (int nt = 0; nt < 8; ++nt)
#pragma unroll
      for (int j = 0; j < 4; ++j) {
        const int r  = mt * 16 + g * 4 + j;
        const int dc = dw + nt * 16 + m;
        Ob[(size_t)r * DD + dc] = oacc[mt][nt][j] * (mt ? i1[j] : i0[j]);
      }
}

// ---------------- fallback (round-2 kernel, proven) ----------------
#define FB_VSTR 18
__device__ __forceinline__ u32 fb_rn16(u32 bb) { return (bb + 0x8000u) & 0xffff0000u; }
__device__ __forceinline__ u32 fb_pack(float x0, float x1) {
  return fb_rn16(__float_as_uint(x1)) | (fb_rn16(__float_as_uint(x0)) >> 16);
}
union FbFrag { u32 u[4]; u32x4_t u4; bf16x8 v; };
__device__ __forceinline__ void fb_cvt(const float* x, FbFrag& fh, FbFrag& fl) {
#pragma unroll
  for (int i = 0; i < 4; ++i) {
    float x0 = x[2 * i], x1 = x[2 * i + 1];
    u32 h0 = fb_rn16(__float_as_uint(x0));
    u32 h1 = fb_rn16(__float_as_uint(x1));
    fh.u[i] = h1 | (h0 >> 16);
    fl.u[i] = fb_pack(x0 - __uint_as_float(h0), x1 - __uint_as_float(h1));
  }
}

__global__ __launch_bounds__(512, 2)
void attn_fb(const float* __restrict__ Qg, const float* __restrict__ Ag,
             float* __restrict__ Og) {
  __shared__ u32 vT[8][128 * FB_VSTR];
  __shared__ float sp[8][32][36];
  __shared__ float ssum[32][36];
  const int tid = threadIdx.x, w = tid >> 6, lane = tid & 63, g = lane >> 4, m = lane & 15;
  const int bid = (int)blockIdx.x, b = bid >> 6, ablk = bid & 63, dw = w * 128;
  const float* Qb = Qg + (size_t)b * SEQ * DD;
  const float* Abase = Ag + ((size_t)b * SEQ + ablk * 32) * DD;
  float* Ob = Og + ((size_t)b * SEQ + ablk * 32) * DD;
  FbFrag ah[2][4], al[2][4];
#pragma unroll
  for (int rt = 0; rt < 2; ++rt)
#pragma unroll
    for (int kt = 0; kt < 4; ++kt) {
      const float* src = Abase + (size_t)(rt * 16 + m) * DD + dw + kt * 32 + g * 8;
      f32x4 v0 = ((const f32x4*)src)[0], v1 = ((const f32x4*)src)[1];
      float x[8];
#pragma unroll
      for (int i = 0; i < 4; ++i) { x[i] = v0[i]; x[4 + i] = v1[i]; }
      fb_cvt(x, ah[rt][kt], al[rt][kt]);
    }
  f32x4 oacc[2][8];
#pragma unroll
  for (int mt = 0; mt < 2; ++mt)
#pragma unroll
    for (int nt = 0; nt < 8; ++nt) oacc[mt][nt] = z4();
  float M0 = -1e30f, M1 = -1e30f, L0 = 0.f, L1 = 0.f;
  u32* vTw = &vT[w][0];
#pragma unroll 1
  for (int kb = 0; kb < NKB; ++kb) {
    const int kv0 = kb * KVB;
    f32x4 st[2][2];
#pragma unroll
    for (int ct = 0; ct < 2; ++ct)
#pragma unroll
      for (int rt = 0; rt < 2; ++rt) st[ct][rt] = z4();
#pragma unroll
    for (int kt = 0; kt < 4; ++kt) {
      FbFrag qh[2], ql[2];
#pragma unroll
      for (int kvt = 0; kvt < 2; ++kvt) {
        const float* src = Qb + (size_t)(kv0 + kvt * 16 + m) * DD + dw + kt * 32 + g * 8;
        f32x4 v0 = ((const f32x4*)src)[0], v1 = ((const f32x4*)src)[1];
        float x[8];
#pragma unroll
        for (int i = 0; i < 4; ++i) { x[i] = v0[i]; x[4 + i] = v1[i]; }
        fb_cvt(x, qh[kvt], ql[kvt]);
      }
      const int dbase = kt * 32 + g * 8;
#pragma unroll
      for (int i = 0; i < 4; ++i) {
        u32 we = (qh[1].u[i] << 16) | (qh[0].u[i] & 0xffffu);
        u32 wo = (qh[1].u[i] & 0xffff0000u) | (qh[0].u[i] >> 16);
        vTw[(dbase + 2 * i) * FB_VSTR + m] = we;
        vTw[(dbase + 2 * i + 1) * FB_VSTR + m] = wo;
      }
#pragma unroll
      for (int ct = 0; ct < 2; ++ct)
#pragma unroll
        for (int rt = 0; rt < 2; ++rt) {
          st[ct][rt] = __builtin_amdgcn_mfma_f32_16x16x32_bf16(qh[ct].v, ah[rt][kt].v, st[ct][rt], 0, 0, 0);
          st[ct][rt] = __builtin_amdgcn_mfma_f32_16x16x32_bf16(qh[ct].v, al[rt][kt].v, st[ct][rt], 0, 0, 0);
          st[ct][rt] = __builtin_amdgcn_mfma_f32_16x16x32_bf16(ql[ct].v, ah[rt][kt].v, st[ct][rt], 0, 0, 0);
        }
    }
#pragma unroll
    for (int ct = 0; ct < 2; ++ct)
#pragma unroll
      for (int rt = 0; rt < 2; ++rt)
        *(f32x4*)&sp[w][rt * 16 + m][ct * 16 + g * 4] = st[ct][rt];
    __syncthreads();
#pragma unroll
    for (int rep = 0; rep < 2; ++rep) {
      const int pp = tid + rep * 512;
      const int r = pp >> 5, c = pp & 31;
      float acc = 0.f;
#pragma unroll
      for (int ww = 0; ww < 8; ++ww) acc += sp[ww][r][c];
      ssum[r][c] = acc;
    }
    __syncthreads();
    f32x4 sv[2][2];
#pragma unroll
    for (int ct = 0; ct < 2; ++ct)
#pragma unroll
      for (int rt = 0; rt < 2; ++rt)
        sv[ct][rt] = *(const f32x4*)&ssum[rt * 16 + m][ct * 16 + g * 4];
    float mx0 = -1e30f, mx1 = -1e30f;
#pragma unroll
    for (int ct = 0; ct < 2; ++ct)
#pragma unroll
      for (int j = 0; j < 4; ++j) {
        mx0 = fmaxf(mx0, sv[ct][0][j]);
        mx1 = fmaxf(mx1, sv[ct][1][j]);
      }
    mx0 = fmaxf(mx0, __shfl_xor(mx0, 16));
    mx0 = fmaxf(mx0, __shfl_xor(mx0, 32));
    mx1 = fmaxf(mx1, __shfl_xor(mx1, 16));
    mx1 = fmaxf(mx1, __shfl_xor(mx1, 32));
    if (__any((mx0 > M0) | (mx1 > M1))) {
      const float nM0 = fmaxf(M0, mx0), nM1 = fmaxf(M1, mx1);
      const float c0 = __expf(M0 - nM0), c1 = __expf(M1 - nM1);
      M0 = nM0; M1 = nM1; L0 *= c0; L1 *= c1;
      f32x4 cr0, cr1;
#pragma unroll
      for (int j = 0; j < 4; ++j) { cr0[j] = __shfl(c0, g * 4 + j); cr1[j] = __shfl(c1, g * 4 + j); }
#pragma unroll
      for (int nt = 0; nt < 8; ++nt)
#pragma unroll
        for (int j = 0; j < 4; ++j) { oacc[0][nt][j] *= cr0[j]; oacc[1][nt][j] *= cr1[j]; }
    }
    f32x4 p00, p10, p01, p11;
#pragma unroll
    for (int j = 0; j < 4; ++j) {
      p00[j] = __expf(sv[0][0][j] - M0);
      p10[j] = __expf(sv[1][0][j] - M0);
      p01[j] = __expf(sv[0][1][j] - M1);
      p11[j] = __expf(sv[1][1][j] - M1);
    }
    float rs0 = 0.f, rs1 = 0.f;
#pragma unroll
    for (int j = 0; j < 4; ++j) { rs0 += p00[j] + p10[j]; rs1 += p01[j] + p11[j]; }
    rs0 += __shfl_xor(rs0, 16); rs0 += __shfl_xor(rs0, 32);
    rs1 += __shfl_xor(rs1, 16); rs1 += __shfl_xor(rs1, 32);
    L0 += rs0; L1 += rs1;
    FbFrag pa0, pa1;
#pragma unroll
    for (int j = 0; j < 4; ++j) {
      pa0.u[j] = fb_pack(p00[j], p10[j]);
      pa1.u[j] = fb_pack(p01[j], p11[j]);
    }
#pragma unroll
    for (int nt = 0; nt < 8; ++nt) {
      const u32* src = &vTw[(nt * 16 + m) * FB_VSTR + g * 4];
      FbFrag bq;
      *(u32x2_t*)&bq.u[0] = *(const u32x2_t*)&src[0];
      *(u32x2_t*)&bq.u[2] = *(const u32x2_t*)&src[2];
      oacc[0][nt] = __builtin_amdgcn_mfma_f32_16x16x32_bf16(pa0.v, bq.v, oacc[0][nt], 0, 0, 0);
      oacc[1][nt] = __builtin_amdgcn_mfma_f32_16x16x32_bf16(pa1.v, bq.v, oacc[1][nt], 0, 0, 0);
    }
  }
  f32x4 i0, i1;
#pragma unroll
  for (int j = 0; j < 4; ++j) {
    i0[j] = 1.f / __shfl(L0, g * 4 + j);
    i1[j] = 1.f / __shfl(L1, g * 4 + j);
  }
#pragma unroll
  for (int mt = 0; mt < 2; ++mt)
#pragma unroll
    for (int nt = 0; nt < 8; ++nt)
#pragma unroll
      for (int j = 0; j < 4; ++j) {
        const int r = mt * 16 + g * 4 + j;
        const int dc = dw + nt * 16 + m;
        Ob[(size_t)r * DD + dc] = oacc[mt][nt][j] * (mt ? i1[j] : i0[j]);
      }
}

extern "C" void kernel_launch(void* const* d_in, const int* in_sizes, int n_in,
                              void* d_out, int out_size, void* d_ws, size_t ws_size,
                              hipStream_t stream) {
  const float* q = (const float*)d_in[0];
  const float* a = (const float*)d_in[1];
  float* o = (float*)d_out;
  if (ws_size >= WS_NEED) {
    char* ws = (char*)d_ws;
    u32* qti = (u32*)(ws + WS_QTI);
    u16* qhi = (u16*)(ws + WS_QHI);
    u16* qlo = (u16*)(ws + WS_QLO);
    u8*  q8  = (u8*)(ws + WS_Q8);
    prepass<<<NB * 64 * 16, 256, 0, stream>>>(q, qti, qhi, qlo, q8);
    attn_main<<<NB * (SEQ / BM), 1024, 0, stream>>>(a, qti, qhi, qlo, q8, o);
  } else {
    attn_fb<<<NB * (SEQ / 32), 512, 0, stream>>>(q, a, o);
  }
  (void)in_sizes; (void)n_in; (void)out_size;
}

// Round 5
// 1976.352 us; speedup vs baseline: 1.5556x; 1.5556x over previous
//
#include <hip/hip_runtime.h>
#include <stdint.h>

typedef short bf16x8 __attribute__((ext_vector_type(8)));
typedef _Float16 f16x8 __attribute__((ext_vector_type(8)));
typedef float f32x4 __attribute__((ext_vector_type(4)));
typedef unsigned int u32x2_t __attribute__((ext_vector_type(2)));
typedef unsigned int u32x4_t __attribute__((ext_vector_type(4)));
typedef unsigned int u32;
typedef unsigned short u16;
typedef unsigned char u8;
typedef unsigned long long u64;

#define NB  16
#define SEQ 2048
#define DD  1024
#define BM  32     // a-rows per WG
#define KVB 32
#define NWAVE 8
#define NKB (SEQ / KVB)

// d_ws layout (bytes):
//   QIL [b][kv][32 blocks x (32 f16 hi | 32 f16 lo)] : 4 B / real elem -> 128 MB
//   QTI [b][d][1024 u32] pair-interleaved f16-hi Q^T : 64 MB
#define WS_QIL 0ULL
#define WS_QTI (128ULL << 20)
#define WS_NEED (192ULL << 20)

union HF { u32 u[4]; u32x4_t u4; f16x8 v; };

__device__ __forceinline__ f32x4 z4() {
  f32x4 v; v[0] = 0.f; v[1] = 0.f; v[2] = 0.f; v[3] = 0.f; return v;
}
__device__ __forceinline__ float h16(float x) {
  // round-to-nearest f16-representable value, kept in f32
  return __uint_as_float((__float_as_uint(x) + 0x1000u) & 0xFFFFE000u);
}
__device__ __forceinline__ u32 packh(float a, float b) {
  auto t = __builtin_amdgcn_cvt_pkrtz(a, b);
  return *(u32*)&t;
}
__device__ __forceinline__ f32x4 mfma16(f16x8 a, f16x8 b, f32x4 c) {
  return __builtin_amdgcn_mfma_f32_16x16x32_f16(a, b, c, 0, 0, 0);
}

// ---------------- prepass: q -> QIL (hi/lo block-interleaved) + QTI ----------------
__global__ __launch_bounds__(256)
void prepass(const float* __restrict__ Q, u8* __restrict__ QIL, u32* __restrict__ QTI) {
  __shared__ u16 hl[32][72];
  const int t = threadIdx.x;
  const int bidx = (int)blockIdx.x;          // b*1024 + kvb*16 + db
  const int db = bidx & 15, kvb = (bidx >> 4) & 63, b = bidx >> 10;
  const int r = t >> 3, dc = (t & 7) * 8;
  const int kv = kvb * 32 + r;
  const size_t row = (size_t)(b * SEQ + kv) * DD + db * 64 + dc;
  f32x4 v0 = ((const f32x4*)(Q + row))[0];
  f32x4 v1 = ((const f32x4*)(Q + row))[1];
  float e[8] = { v0[0], v0[1], v0[2], v0[3], v1[0], v1[1], v1[2], v1[3] };
  float hh[8], ll[8];
#pragma unroll
  for (int i = 0; i < 8; ++i) { hh[i] = h16(e[i]); ll[i] = e[i] - hh[i]; }
  u32x4_t hw, lw;
#pragma unroll
  for (int j = 0; j < 4; ++j) {
    hw[j] = packh(hh[2 * j], hh[2 * j + 1]);   // exact (hh is f16-representable)
    lw[j] = packh(ll[2 * j], ll[2 * j + 1]);
  }
  // QIL: per row, 32 blocks of 128 B: [hi 32 f16][lo 32 f16]
  const int D0 = db * 64 + dc;                 // first real d of this thread
  const size_t rb = (size_t)(b * SEQ + kv) * 4096;
  u8* dsth = QIL + rb + (size_t)(D0 >> 5) * 128 + (D0 & 31) * 2;
  *(u32x4_t*)dsth        = hw;
  *(u32x4_t*)(dsth + 64) = lw;
  // QTI staging (f16 hi, transposed, (kv, kv+16) pair-interleaved)
#pragma unroll
  for (int j = 0; j < 4; ++j) {
    hl[r][dc + 2 * j]     = (u16)(hw[j] & 0xffffu);
    hl[r][dc + 2 * j + 1] = (u16)(hw[j] >> 16);
  }
  __syncthreads();
  const int d = t >> 2, i4 = (t & 3) * 4;
  u32x4_t w;
#pragma unroll
  for (int ii = 0; ii < 4; ++ii) {
    const int i = i4 + ii;
    w[ii] = (u32)hl[i][d] | ((u32)hl[i + 16][d] << 16);  // (kv0+i, kv0+16+i)
  }
  u32* dst = QTI + ((size_t)(b * DD + db * 64 + d)) * 1024 + kvb * 16 + i4;
  *(u32x4_t*)dst = w;
}

// ---------------- main fused kernel (8 waves, BM=32, d-split) ----------------
__global__ __launch_bounds__(512, 2)
void attn_main(const float* __restrict__ Ag, const u8* __restrict__ QIL,
               const u32* __restrict__ QTI, float* __restrict__ Og) {
  __shared__ float sp[NWAVE][BM][36];   // per-wave partial S^T (36864 B)
  __shared__ float ssum[BM][36];        // reduced S^T          ( 4608 B)

  const int tid  = (int)threadIdx.x;
  const int w    = tid >> 6;
  const int lane = tid & 63;
  const int g    = lane >> 4;
  const int m    = lane & 15;
  const int dw   = w * 128;

  // XCD chunk swizzle: 1024 = 8 * 128 (bijective)
  const int p = (int)blockIdx.x;
  const int l = (p & 7) * 128 + (p >> 3);
  const int b = l >> 6;
  const int ablk = l & 63;

  const float* Abase = Ag + ((size_t)(b * SEQ + ablk * BM)) * DD;
  float*       Ob    = Og + ((size_t)(b * SEQ + ablk * BM)) * DD;
  const u8*  Qb  = QIL + (size_t)(b * SEQ) * 4096 + w * 512;
  const u32* Vb  = QTI + ((size_t)(b * DD + dw + m)) * 1024 + g * 4;

  // ---- prologue: A-tile -> f16-hi fragments (regs only; lo never needed)
  f16x8 ah[2][4];
#pragma unroll
  for (int rt = 0; rt < 2; ++rt) {
#pragma unroll
    for (int kt = 0; kt < 4; ++kt) {
      const float* src = Abase + (size_t)(rt * 16 + m) * DD + dw + kt * 32 + g * 8;
      f32x4 v0 = ((const f32x4*)src)[0];
      f32x4 v1 = ((const f32x4*)src)[1];
      float e[8] = { v0[0], v0[1], v0[2], v0[3], v1[0], v1[1], v1[2], v1[3] };
      HF fh;
#pragma unroll
      for (int j = 0; j < 4; ++j) fh.u[j] = packh(h16(e[2 * j]), h16(e[2 * j + 1]));
      ah[rt][kt] = fh.v;
    }
  }

  f32x4 oacc[2][8];
#pragma unroll
  for (int mt = 0; mt < 2; ++mt)
#pragma unroll
    for (int nt = 0; nt < 8; ++nt) oacc[mt][nt] = z4();

  float M0 = -1e30f, M1 = -1e30f, L0 = 0.f, L1 = 0.f;

#pragma unroll 1
  for (int kb = 0; kb < NKB; ++kb) {
    const int kv0 = kb * KVB;

    // ---- issue ALL Q loads for this kb up front (single interleaved stream)
    HF q[2][8];
#pragma unroll
    for (int ct = 0; ct < 2; ++ct) {
      const u8* prow = Qb + (size_t)(kv0 + ct * 16 + m) * 4096 + g * 16;
#pragma unroll
      for (int v = 0; v < 8; ++v)
        q[ct][v].u4 = *(const u32x4_t*)(prow + v * 64);
    }

    // ---- S^T partial: virtual-K 256 (hi/lo interleaved), ah[v>>1] serves both halves
    f32x4 st[2][2];
#pragma unroll
    for (int ct = 0; ct < 2; ++ct)
#pragma unroll
      for (int rt = 0; rt < 2; ++rt) st[ct][rt] = z4();
#pragma unroll
    for (int ct = 0; ct < 2; ++ct)
#pragma unroll
      for (int v = 0; v < 8; ++v) {
        st[ct][0] = mfma16(q[ct][v].v, ah[0][v >> 1], st[ct][0]);
        st[ct][1] = mfma16(q[ct][v].v, ah[1][v >> 1], st[ct][1]);
      }

    // ---- stage A: per-wave partials
#pragma unroll
    for (int ct = 0; ct < 2; ++ct)
#pragma unroll
      for (int rt = 0; rt < 2; ++rt)
        *(f32x4*)&sp[w][rt * 16 + m][ct * 16 + g * 4] = st[ct][rt];
    __syncthreads();

    // ---- stage B: cross-wave reduce (512 threads x 2 positions)
#pragma unroll
    for (int rep = 0; rep < 2; ++rep) {
      const int pp = tid + rep * 512;
      const int r = pp >> 5, c = pp & 31;
      float acc = sp[0][r][c];
#pragma unroll
      for (int ww = 1; ww < NWAVE; ++ww) acc += sp[ww][r][c];
      ssum[r][c] = acc;
    }
    __syncthreads();

    // ---- PV B-operand loads early (softmax VALU below covers their latency)
    const u32* vrow = Vb + kb * 16;
    u32x4_t bq[8];
#pragma unroll
    for (int nt = 0; nt < 8; ++nt)
      bq[nt] = *(const u32x4_t*)(vrow + (size_t)nt * 16 * 1024);

    // ---- full S^T in C-fragment layout; online softmax (redundant per wave)
    f32x4 sv[2][2];
#pragma unroll
    for (int ct = 0; ct < 2; ++ct)
#pragma unroll
      for (int rt = 0; rt < 2; ++rt)
        sv[ct][rt] = *(const f32x4*)&ssum[rt * 16 + m][ct * 16 + g * 4];

    float mx0 = -1e30f, mx1 = -1e30f;
#pragma unroll
    for (int ct = 0; ct < 2; ++ct)
#pragma unroll
      for (int j = 0; j < 4; ++j) {
        mx0 = fmaxf(mx0, sv[ct][0][j]);
        mx1 = fmaxf(mx1, sv[ct][1][j]);
      }
    mx0 = fmaxf(mx0, __shfl_xor(mx0, 16));
    mx0 = fmaxf(mx0, __shfl_xor(mx0, 32));
    mx1 = fmaxf(mx1, __shfl_xor(mx1, 16));
    mx1 = fmaxf(mx1, __shfl_xor(mx1, 32));

    if (__any((mx0 > M0) | (mx1 > M1))) {
      const float nM0 = fmaxf(M0, mx0), nM1 = fmaxf(M1, mx1);
      const float c0 = __expf(M0 - nM0), c1 = __expf(M1 - nM1);
      M0 = nM0; M1 = nM1;
      L0 *= c0; L1 *= c1;
      f32x4 cr0, cr1;
#pragma unroll
      for (int j = 0; j < 4; ++j) {
        cr0[j] = __shfl(c0, g * 4 + j);
        cr1[j] = __shfl(c1, g * 4 + j);
      }
#pragma unroll
      for (int nt = 0; nt < 8; ++nt)
#pragma unroll
        for (int j = 0; j < 4; ++j) {
          oacc[0][nt][j] *= cr0[j];
          oacc[1][nt][j] *= cr1[j];
        }
    }

    f32x4 p00, p10, p01, p11;   // [ct][row-half]
#pragma unroll
    for (int j = 0; j < 4; ++j) {
      p00[j] = __expf(sv[0][0][j] - M0);
      p10[j] = __expf(sv[1][0][j] - M0);
      p01[j] = __expf(sv[0][1][j] - M1);
      p11[j] = __expf(sv[1][1][j] - M1);
    }
    float rs0 = 0.f, rs1 = 0.f;
#pragma unroll
    for (int j = 0; j < 4; ++j) {
      rs0 += p00[j] + p10[j];
      rs1 += p01[j] + p11[j];
    }
    rs0 += __shfl_xor(rs0, 16); rs0 += __shfl_xor(rs0, 32);
    rs1 += __shfl_xor(rs1, 16); rs1 += __shfl_xor(rs1, 32);
    L0 += rs0; L1 += rs1;

    HF pa0, pa1;  // u[j]: lo=kv0+g*4+j, hi=kv0+16+g*4+j (matches QTI words)
#pragma unroll
    for (int j = 0; j < 4; ++j) {
      pa0.u[j] = packh(p00[j], p10[j]);
      pa1.u[j] = packh(p01[j], p11[j]);
    }

    // ---- PV: A = P (regs, f16), B = V fragments (preloaded)
#pragma unroll
    for (int nt = 0; nt < 8; ++nt) {
      HF bqv; bqv.u4 = bq[nt];
      oacc[0][nt] = mfma16(pa0.v, bqv.v, oacc[0][nt]);
      oacc[1][nt] = mfma16(pa1.v, bqv.v, oacc[1][nt]);
    }
  }

  // ---- epilogue: normalize by L and store
  f32x4 i0, i1;
#pragma unroll
  for (int j = 0; j < 4; ++j) {
    i0[j] = 1.f / __shfl(L0, g * 4 + j);
    i1[j] = 1.f / __shfl(L1, g * 4 + j);
  }
#pragma unroll
  for (int mt = 0; mt < 2; ++mt)
#pragma unroll
    for (int nt = 0; nt < 8; ++nt)
#pragma unroll
      for (int j = 0; j < 4; ++j) {
        const int r  = mt * 16 + g * 4 + j;
        const int dc = dw + nt * 16 + m;
        Ob[(size_t)r * DD + dc] = oacc[mt][nt][j] * (mt ? i1[j] : i0[j]);
      }
}

// ---------------- fallback (round-2 kernel, proven 1388 us) ----------------
#define FB_VSTR 18
__device__ __forceinline__ u32 fb_rn16(u32 bb) { return (bb + 0x8000u) & 0xffff0000u; }
__device__ __forceinline__ u32 fb_pack(float x0, float x1) {
  return fb_rn16(__float_as_uint(x1)) | (fb_rn16(__float_as_uint(x0)) >> 16);
}
union FbFrag { u32 u[4]; u32x4_t u4; bf16x8 v; };
__device__ __forceinline__ void fb_cvt(const float* x, FbFrag& fh, FbFrag& fl) {
#pragma unroll
  for (int i = 0; i < 4; ++i) {
    float x0 = x[2 * i], x1 = x[2 * i + 1];
    u32 h0 = fb_rn16(__float_as_uint(x0));
    u32 h1 = fb_rn16(__float_as_uint(x1));
    fh.u[i] = h1 | (h0 >> 16);
    fl.u[i] = fb_pack(x0 - __uint_as_float(h0), x1 - __uint_as_float(h1));
  }
}

__global__ __launch_bounds__(512, 2)
void attn_fb(const float* __restrict__ Qg, const float* __restrict__ Ag,
             float* __restrict__ Og) {
  __shared__ u32 vT[8][128 * FB_VSTR];
  __shared__ float sp[8][32][36];
  __shared__ float ssum[32][36];
  const int tid = threadIdx.x, w = tid >> 6, lane = tid & 63, g = lane >> 4, m = lane & 15;
  const int bid = (int)blockIdx.x, b = bid >> 6, ablk = bid & 63, dw = w * 128;
  const float* Qb = Qg + (size_t)b * SEQ * DD;
  const float* Abase = Ag + ((size_t)b * SEQ + ablk * 32) * DD;
  float* Ob = Og + ((size_t)b * SEQ + ablk * 32) * DD;
  FbFrag ah[2][4], al[2][4];
#pragma unroll
  for (int rt = 0; rt < 2; ++rt)
#pragma unroll
    for (int kt = 0; kt < 4; ++kt) {
      const float* src = Abase + (size_t)(rt * 16 + m) * DD + dw + kt * 32 + g * 8;
      f32x4 v0 = ((const f32x4*)src)[0], v1 = ((const f32x4*)src)[1];
      float x[8];
#pragma unroll
      for (int i = 0; i < 4; ++i) { x[i] = v0[i]; x[4 + i] = v1[i]; }
      fb_cvt(x, ah[rt][kt], al[rt][kt]);
    }
  f32x4 oacc[2][8];
#pragma unroll
  for (int mt = 0; mt < 2; ++mt)
#pragma unroll
    for (int nt = 0; nt < 8; ++nt) oacc[mt][nt] = z4();
  float M0 = -1e30f, M1 = -1e30f, L0 = 0.f, L1 = 0.f;
  u32* vTw = &vT[w][0];
#pragma unroll 1
  for (int kb = 0; kb < NKB; ++kb) {
    const int kv0 = kb * KVB;
    f32x4 st[2][2];
#pragma unroll
    for (int ct = 0; ct < 2; ++ct)
#pragma unroll
      for (int rt = 0; rt < 2; ++rt) st[ct][rt] = z4();
#pragma unroll
    for (int kt = 0; kt < 4; ++kt) {
      FbFrag qh[2], ql[2];
#pragma unroll
      for (int kvt = 0; kvt < 2; ++kvt) {
        const float* src = Qb + (size_t)(kv0 + kvt * 16 + m) * DD + dw + kt * 32 + g * 8;
        f32x4 v0 = ((const f32x4*)src)[0], v1 = ((const f32x4*)src)[1];
        float x[8];
#pragma unroll
        for (int i = 0; i < 4; ++i) { x[i] = v0[i]; x[4 + i] = v1[i]; }
        fb_cvt(x, qh[kvt], ql[kvt]);
      }
      const int dbase = kt * 32 + g * 8;
#pragma unroll
      for (int i = 0; i < 4; ++i) {
        u32 we = (qh[1].u[i] << 16) | (qh[0].u[i] & 0xffffu);
        u32 wo = (qh[1].u[i] & 0xffff0000u) | (qh[0].u[i] >> 16);
        vTw[(dbase + 2 * i) * FB_VSTR + m] = we;
        vTw[(dbase + 2 * i + 1) * FB_VSTR + m] = wo;
      }
#pragma unroll
      for (int ct = 0; ct < 2; ++ct)
#pragma unroll
        for (int rt = 0; rt < 2; ++rt) {
          st[ct][rt] = __builtin_amdgcn_mfma_f32_16x16x32_bf16(qh[ct].v, ah[rt][kt].v, st[ct][rt], 0, 0, 0);
          st[ct][rt] = __builtin_amdgcn_mfma_f32_16x16x32_bf16(qh[ct].v, al[rt][kt].v, st[ct][rt], 0, 0, 0);
          st[ct][rt] = __builtin_amdgcn_mfma_f32_16x16x32_bf16(ql[ct].v, ah[rt][kt].v, st[ct][rt], 0, 0, 0);
        }
    }
#pragma unroll
    for (int ct = 0; ct < 2; ++ct)
#pragma unroll
      for (int rt = 0; rt < 2; ++rt)
        *(f32x4*)&sp[w][rt * 16 + m][ct * 16 + g * 4] = st[ct][rt];
    __syncthreads();
#pragma unroll
    for (int rep = 0; rep < 2; ++rep) {
      const int pp = tid + rep * 512;
      const int r = pp >> 5, c = pp & 31;
      float acc = 0.f;
#pragma unroll
      for (int ww = 0; ww < 8; ++ww) acc += sp[ww][r][c];
      ssum[r][c] = acc;
    }
    __syncthreads();
    f32x4 sv[2][2];
#pragma unroll
    for (int ct = 0; ct < 2; ++ct)
#pragma unroll
      for (int rt = 0; rt < 2; ++rt)
        sv[ct][rt] = *(const f32x4*)&ssum[rt * 16 + m][ct * 16 + g * 4];
    float mx0 = -1e30f, mx1 = -1e30f;
#pragma unroll
    for (int ct = 0; ct < 2; ++ct)
#pragma unroll
      for (int j = 0; j < 4; ++j) {
        mx0 = fmaxf(mx0, sv[ct][0][j]);
        mx1 = fmaxf(mx1, sv[ct][1][j]);
      }
    mx0 = fmaxf(mx0, __shfl_xor(mx0, 16));
    mx0 = fmaxf(mx0, __shfl_xor(mx0, 32));
    mx1 = fmaxf(mx1, __shfl_xor(mx1, 16));
    mx1 = fmaxf(mx1, __shfl_xor(mx1, 32));
    if (__any((mx0 > M0) | (mx1 > M1))) {
      const float nM0 = fmaxf(M0, mx0), nM1 = fmaxf(M1, mx1);
      const float c0 = __expf(M0 - nM0), c1 = __expf(M1 - nM1);
      M0 = nM0; M1 = nM1; L0 *= c0; L1 *= c1;
      f32x4 cr0, cr1;
#pragma unroll
      for (int j = 0; j < 4; ++j) { cr0[j] = __shfl(c0, g * 4 + j); cr1[j] = __shfl(c1, g * 4 + j); }
#pragma unroll
      for (int nt = 0; nt < 8; ++nt)
#pragma unroll
        for (int j = 0; j < 4; ++j) { oacc[0][nt][j] *= cr0[j]; oacc[1][nt][j] *= cr1[j]; }
    }
    f32x4 p00, p10, p01, p11;
#pragma unroll
    for (int j = 0; j < 4; ++j) {
      p00[j] = __expf(sv[0][0][j] - M0);
      p10[j] = __expf(sv[1][0][j] - M0);
      p01[j] = __expf(sv[0][1][j] - M1);
      p11[j] = __expf(sv[1][1][j] - M1);
    }
    float rs0 = 0.f, rs1 = 0.f;
#pragma unroll
    for (int j = 0; j < 4; ++j) { rs0 += p00[j] + p10[j]; rs1 += p01[j] + p11[j]; }
    rs0 += __shfl_xor(rs0, 16); rs0 += __shfl_xor(rs0, 32);
    rs1 += __shfl_xor(rs1, 16); rs1 += __shfl_xor(rs1, 32);
    L0 += rs0; L1 += rs1;
    FbFrag pa0, pa1;
#pragma unroll
    for (int j = 0; j < 4; ++j) {
      pa0.u[j] = fb_pack(p00[j], p10[j]);
      pa1.u[j] = fb_pack(p01[j], p11[j]);
    }
#pragma unroll
    for (int nt = 0; nt < 8; ++nt) {
      const u32* src = &vTw[(nt * 16 + m) * FB_VSTR + g * 4];
      FbFrag bq;
      *(u32x2_t*)&bq.u[0] = *(const u32x2_t*)&src[0];
      *(u32x2_t*)&bq.u[2] = *(const u32x2_t*)&src[2];
      oacc[0][nt] = __builtin_amdgcn_mfma_f32_16x16x32_bf16(pa0.v, bq.v, oacc[0][nt], 0, 0, 0);
      oacc[1][nt] = __builtin_amdgcn_mfma_f32_16x16x32_bf16(pa1.v, bq.v, oacc[1][nt], 0, 0, 0);
    }
  }
  f32x4 i0, i1;
#pragma unroll
  for (int j = 0; j < 4; ++j) {
    i0[j] = 1.f / __shfl(L0, g * 4 + j);
    i1[j] = 1.f / __shfl(L1, g * 4 + j);
  }
#pragma unroll
  for (int mt = 0; mt < 2; ++mt)
#pragma unroll
    for (int nt = 0; nt < 8; ++nt)
#pragma unroll
      for (int j = 0; j < 4; ++j) {
        const int r = mt * 16 + g * 4 + j;
        const int dc = dw + nt * 16 + m;
        Ob[(size_t)r * DD + dc] = oacc[mt][nt][j] * (mt ? i1[j] : i0[j]);
      }
}

extern "C" void kernel_launch(void* const* d_in, const int* in_sizes, int n_in,
                              void* d_out, int out_size, void* d_ws, size_t ws_size,
                              hipStream_t stream) {
  const float* q = (const float*)d_in[0];
  const float* a = (const float*)d_in[1];
  float* o = (float*)d_out;
  if (ws_size >= WS_NEED) {
    char* ws = (char*)d_ws;
    u8*  qil = (u8*)(ws + WS_QIL);
    u32* qti = (u32*)(ws + WS_QTI);
    prepass<<<NB * 64 * 16, 256, 0, stream>>>(q, qil, qti);
    attn_main<<<NB * (SEQ / BM), 512, 0, stream>>>(a, qil, qti, o);
  } else {
    attn_fb<<<NB * (SEQ / 32), 512, 0, stream>>>(q, a, o);
  }
  (void)in_sizes; (void)n_in; (void)out_size;
}

// Round 6
// 1081.637 us; speedup vs baseline: 2.8423x; 1.8272x over previous
//
#include <hip/hip_runtime.h>
#include <stdint.h>

typedef short bf16x8 __attribute__((ext_vector_type(8)));
typedef _Float16 f16x8 __attribute__((ext_vector_type(8)));
typedef float f32x4 __attribute__((ext_vector_type(4)));
typedef unsigned int u32x2_t __attribute__((ext_vector_type(2)));
typedef unsigned int u32x4_t __attribute__((ext_vector_type(4)));
typedef unsigned int u32;
typedef unsigned short u16;
typedef unsigned char u8;
typedef unsigned long long u64;

#define NB  16
#define SEQ 2048
#define DD  1024
#define BM  32     // a-rows per WG
#define KVB 32
#define NWAVE 8
#define NKB (SEQ / KVB)

// d_ws layout (bytes):
//   QH  [b][kv][d] f16 (round-to-nearest)              : 64 MB
//   QTI [b][d][1024 u32] pair-interleaved f16 Q^T      : 64 MB
#define WS_QH  0ULL
#define WS_QTI (64ULL << 20)
#define WS_NEED (128ULL << 20)

union HF { u32 u[4]; u32x4_t u4; f16x8 v; };

__device__ __forceinline__ f32x4 z4() {
  f32x4 v; v[0] = 0.f; v[1] = 0.f; v[2] = 0.f; v[3] = 0.f; return v;
}
__device__ __forceinline__ float h16(float x) {
  // round-to-nearest f16-representable value, kept in f32
  return __uint_as_float((__float_as_uint(x) + 0x1000u) & 0xFFFFE000u);
}
__device__ __forceinline__ u32 packh(float a, float b) {
  auto t = __builtin_amdgcn_cvt_pkrtz(a, b);   // exact when inputs f16-representable
  return *(u32*)&t;
}
__device__ __forceinline__ f32x4 mfma16(f16x8 a, f16x8 b, f32x4 c) {
  return __builtin_amdgcn_mfma_f32_16x16x32_f16(a, b, c, 0, 0, 0);
}

// ---------------- prepass: q -> QH (f16 rows) + QTI (transposed pair-interleaved) ----------------
__global__ __launch_bounds__(256)
void prepass(const float* __restrict__ Q, u16* __restrict__ QH, u32* __restrict__ QTI) {
  __shared__ u16 hl[32][72];
  const int t = threadIdx.x;
  const int bidx = (int)blockIdx.x;          // b*1024 + kvb*16 + db
  const int db = bidx & 15, kvb = (bidx >> 4) & 63, b = bidx >> 10;
  const int r = t >> 3, dc = (t & 7) * 8;
  const int kv = kvb * 32 + r;
  const size_t row = (size_t)(b * SEQ + kv) * DD + db * 64 + dc;
  f32x4 v0 = ((const f32x4*)(Q + row))[0];
  f32x4 v1 = ((const f32x4*)(Q + row))[1];
  float e[8] = { v0[0], v0[1], v0[2], v0[3], v1[0], v1[1], v1[2], v1[3] };
  u32x4_t hw;
#pragma unroll
  for (int j = 0; j < 4; ++j)
    hw[j] = packh(h16(e[2 * j]), h16(e[2 * j + 1]));
  *(u32x4_t*)(QH + row) = hw;
  // QTI staging (f16, transposed, (kv, kv+16) pair-interleaved)
#pragma unroll
  for (int j = 0; j < 4; ++j) {
    hl[r][dc + 2 * j]     = (u16)(hw[j] & 0xffffu);
    hl[r][dc + 2 * j + 1] = (u16)(hw[j] >> 16);
  }
  __syncthreads();
  const int d = t >> 2, i4 = (t & 3) * 4;
  u32x4_t w;
#pragma unroll
  for (int ii = 0; ii < 4; ++ii) {
    const int i = i4 + ii;
    w[ii] = (u32)hl[i][d] | ((u32)hl[i + 16][d] << 16);  // (kv0+i, kv0+16+i)
  }
  u32* dst = QTI + ((size_t)(b * DD + db * 64 + d)) * 1024 + kvb * 16 + i4;
  *(u32x4_t*)dst = w;
}

// ---------------- main fused kernel (8 waves, BM=32, d-split, prefetched) ----------------
__global__ __launch_bounds__(512, 2)
void attn_main(const float* __restrict__ Ag, const u16* __restrict__ QH,
               const u32* __restrict__ QTI, float* __restrict__ Og) {
  __shared__ float sp[NWAVE][BM][36];   // per-wave partial S^T (36864 B)
  __shared__ float ssum[BM][36];        // reduced S^T          ( 4608 B)

  const int tid  = (int)threadIdx.x;
  const int w    = tid >> 6;
  const int lane = tid & 63;
  const int g    = lane >> 4;
  const int m    = lane & 15;
  const int dw   = w * 128;

  // XCD chunk swizzle: 1024 = 8 * 128 (bijective); one batch's 64 WGs share an XCD
  const int p = (int)blockIdx.x;
  const int l = (p & 7) * 128 + (p >> 3);
  const int b = l >> 6;
  const int ablk = l & 63;

  const float* Abase = Ag + ((size_t)(b * SEQ + ablk * BM)) * DD;
  float*       Ob    = Og + ((size_t)(b * SEQ + ablk * BM)) * DD;
  const u16* Qb = QH + (size_t)(b * SEQ) * DD + dw + g * 8;   // + kv*DD + kt*32 at use
  const u32* Vb = QTI + ((size_t)(b * DD + dw + m)) * 1024 + g * 4;

  // ---- prologue: A-tile -> f16 fragments (regs only)
  f16x8 ah[2][4];
#pragma unroll
  for (int rt = 0; rt < 2; ++rt) {
#pragma unroll
    for (int kt = 0; kt < 4; ++kt) {
      const float* src = Abase + (size_t)(rt * 16 + m) * DD + dw + kt * 32 + g * 8;
      f32x4 v0 = ((const f32x4*)src)[0];
      f32x4 v1 = ((const f32x4*)src)[1];
      float e[8] = { v0[0], v0[1], v0[2], v0[3], v1[0], v1[1], v1[2], v1[3] };
      HF fh;
#pragma unroll
      for (int j = 0; j < 4; ++j) fh.u[j] = packh(h16(e[2 * j]), h16(e[2 * j + 1]));
      ah[rt][kt] = fh.v;
    }
  }

  f32x4 oacc[2][8];
#pragma unroll
  for (int mt = 0; mt < 2; ++mt)
#pragma unroll
    for (int nt = 0; nt < 8; ++nt) oacc[mt][nt] = z4();

  float M0 = -1e30f, M1 = -1e30f, L0 = 0.f, L1 = 0.f;

  // ---- initial Q fragment load (kb = 0)
  HF q[2][4];
#pragma unroll
  for (int ct = 0; ct < 2; ++ct)
#pragma unroll
    for (int kt = 0; kt < 4; ++kt)
      q[ct][kt].u4 = *(const u32x4_t*)(Qb + (size_t)(ct * 16 + m) * DD + kt * 32);

#pragma unroll 1
  for (int kb = 0; kb < NKB; ++kb) {
    // ---- PV B-operand loads issued first (covered by S+reduce+softmax)
    const u32* vrow = Vb + kb * 16;
    u32x4_t bq[8];
#pragma unroll
    for (int nt = 0; nt < 8; ++nt)
      bq[nt] = *(const u32x4_t*)(vrow + (size_t)nt * 16 * 1024);

    // ---- S^T partial: kt-outer, 4 independent accumulator chains
    f32x4 st[2][2];
#pragma unroll
    for (int ct = 0; ct < 2; ++ct)
#pragma unroll
      for (int rt = 0; rt < 2; ++rt) st[ct][rt] = z4();
#pragma unroll
    for (int kt = 0; kt < 4; ++kt)
#pragma unroll
      for (int ct = 0; ct < 2; ++ct) {
        st[ct][0] = mfma16(q[ct][kt].v, ah[0][kt], st[ct][0]);
        st[ct][1] = mfma16(q[ct][kt].v, ah[1][kt], st[ct][1]);
      }

    // ---- prefetch next kb's Q into the same registers (lands during reduce/softmax/PV)
    if (kb + 1 < NKB) {
      const int kvn = (kb + 1) * KVB;
#pragma unroll
      for (int ct = 0; ct < 2; ++ct)
#pragma unroll
        for (int kt = 0; kt < 4; ++kt)
          q[ct][kt].u4 = *(const u32x4_t*)(Qb + (size_t)(kvn + ct * 16 + m) * DD + kt * 32);
    }

    // ---- stage A: per-wave partials
#pragma unroll
    for (int ct = 0; ct < 2; ++ct)
#pragma unroll
      for (int rt = 0; rt < 2; ++rt)
        *(f32x4*)&sp[w][rt * 16 + m][ct * 16 + g * 4] = st[ct][rt];
    __syncthreads();

    // ---- stage B: cross-wave reduce (512 threads x 2 positions)
#pragma unroll
    for (int rep = 0; rep < 2; ++rep) {
      const int pp = tid + rep * 512;
      const int r = pp >> 5, c = pp & 31;
      float acc = sp[0][r][c];
#pragma unroll
      for (int ww = 1; ww < NWAVE; ++ww) acc += sp[ww][r][c];
      ssum[r][c] = acc;
    }
    __syncthreads();

    // ---- full S^T in C-fragment layout; online softmax (redundant per wave)
    f32x4 sv[2][2];
#pragma unroll
    for (int ct = 0; ct < 2; ++ct)
#pragma unroll
      for (int rt = 0; rt < 2; ++rt)
        sv[ct][rt] = *(const f32x4*)&ssum[rt * 16 + m][ct * 16 + g * 4];

    float mx0 = -1e30f, mx1 = -1e30f;
#pragma unroll
    for (int ct = 0; ct < 2; ++ct)
#pragma unroll
      for (int j = 0; j < 4; ++j) {
        mx0 = fmaxf(mx0, sv[ct][0][j]);
        mx1 = fmaxf(mx1, sv[ct][1][j]);
      }
    mx0 = fmaxf(mx0, __shfl_xor(mx0, 16));
    mx0 = fmaxf(mx0, __shfl_xor(mx0, 32));
    mx1 = fmaxf(mx1, __shfl_xor(mx1, 16));
    mx1 = fmaxf(mx1, __shfl_xor(mx1, 32));

    if (__any((mx0 > M0) | (mx1 > M1))) {
      const float nM0 = fmaxf(M0, mx0), nM1 = fmaxf(M1, mx1);
      const float c0 = __expf(M0 - nM0), c1 = __expf(M1 - nM1);
      M0 = nM0; M1 = nM1;
      L0 *= c0; L1 *= c1;
      f32x4 cr0, cr1;
#pragma unroll
      for (int j = 0; j < 4; ++j) {
        cr0[j] = __shfl(c0, g * 4 + j);
        cr1[j] = __shfl(c1, g * 4 + j);
      }
#pragma unroll
      for (int nt = 0; nt < 8; ++nt)
#pragma unroll
        for (int j = 0; j < 4; ++j) {
          oacc[0][nt][j] *= cr0[j];
          oacc[1][nt][j] *= cr1[j];
        }
    }

    f32x4 p00, p10, p01, p11;   // [ct][row-half]
#pragma unroll
    for (int j = 0; j < 4; ++j) {
      p00[j] = __expf(sv[0][0][j] - M0);
      p10[j] = __expf(sv[1][0][j] - M0);
      p01[j] = __expf(sv[0][1][j] - M1);
      p11[j] = __expf(sv[1][1][j] - M1);
    }
    float rs0 = 0.f, rs1 = 0.f;
#pragma unroll
    for (int j = 0; j < 4; ++j) {
      rs0 += p00[j] + p10[j];
      rs1 += p01[j] + p11[j];
    }
    rs0 += __shfl_xor(rs0, 16); rs0 += __shfl_xor(rs0, 32);
    rs1 += __shfl_xor(rs1, 16); rs1 += __shfl_xor(rs1, 32);
    L0 += rs0; L1 += rs1;

    HF pa0, pa1;  // u[j]: lo=kv0+g*4+j, hi=kv0+16+g*4+j (matches QTI words)
#pragma unroll
    for (int j = 0; j < 4; ++j) {
      pa0.u[j] = packh(p00[j], p10[j]);
      pa1.u[j] = packh(p01[j], p11[j]);
    }

    // ---- PV: A = P (regs, f16), B = V fragments (preloaded at top)
#pragma unroll
    for (int nt = 0; nt < 8; ++nt) {
      HF bqv; bqv.u4 = bq[nt];
      oacc[0][nt] = mfma16(pa0.v, bqv.v, oacc[0][nt]);
      oacc[1][nt] = mfma16(pa1.v, bqv.v, oacc[1][nt]);
    }
  }

  // ---- epilogue: normalize by L and store
  f32x4 i0, i1;
#pragma unroll
  for (int j = 0; j < 4; ++j) {
    i0[j] = 1.f / __shfl(L0, g * 4 + j);
    i1[j] = 1.f / __shfl(L1, g * 4 + j);
  }
#pragma unroll
  for (int mt = 0; mt < 2; ++mt)
#pragma unroll
    for (int nt = 0; nt < 8; ++nt)
#pragma unroll
      for (int j = 0; j < 4; ++j) {
        const int r  = mt * 16 + g * 4 + j;
        const int dc = dw + nt * 16 + m;
        Ob[(size_t)r * DD + dc] = oacc[mt][nt][j] * (mt ? i1[j] : i0[j]);
      }
}

// ---------------- fallback (round-2 kernel, proven 1388 us) ----------------
#define FB_VSTR 18
__device__ __forceinline__ u32 fb_rn16(u32 bb) { return (bb + 0x8000u) & 0xffff0000u; }
__device__ __forceinline__ u32 fb_pack(float x0, float x1) {
  return fb_rn16(__float_as_uint(x1)) | (fb_rn16(__float_as_uint(x0)) >> 16);
}
union FbFrag { u32 u[4]; u32x4_t u4; bf16x8 v; };
__device__ __forceinline__ void fb_cvt(const float* x, FbFrag& fh, FbFrag& fl) {
#pragma unroll
  for (int i = 0; i < 4; ++i) {
    float x0 = x[2 * i], x1 = x[2 * i + 1];
    u32 h0 = fb_rn16(__float_as_uint(x0));
    u32 h1 = fb_rn16(__float_as_uint(x1));
    fh.u[i] = h1 | (h0 >> 16);
    fl.u[i] = fb_pack(x0 - __uint_as_float(h0), x1 - __uint_as_float(h1));
  }
}

__global__ __launch_bounds__(512, 2)
void attn_fb(const float* __restrict__ Qg, const float* __restrict__ Ag,
             float* __restrict__ Og) {
  __shared__ u32 vT[8][128 * FB_VSTR];
  __shared__ float sp[8][32][36];
  __shared__ float ssum[32][36];
  const int tid = threadIdx.x, w = tid >> 6, lane = tid & 63, g = lane >> 4, m = lane & 15;
  const int bid = (int)blockIdx.x, b = bid >> 6, ablk = bid & 63, dw = w * 128;
  const float* Qb = Qg + (size_t)b * SEQ * DD;
  const float* Abase = Ag + ((size_t)b * SEQ + ablk * 32) * DD;
  float* Ob = Og + ((size_t)b * SEQ + ablk * 32) * DD;
  FbFrag ah[2][4], al[2][4];
#pragma unroll
  for (int rt = 0; rt < 2; ++rt)
#pragma unroll
    for (int kt = 0; kt < 4; ++kt) {
      const float* src = Abase + (size_t)(rt * 16 + m) * DD + dw + kt * 32 + g * 8;
      f32x4 v0 = ((const f32x4*)src)[0], v1 = ((const f32x4*)src)[1];
      float x[8];
#pragma unroll
      for (int i = 0; i < 4; ++i) { x[i] = v0[i]; x[4 + i] = v1[i]; }
      fb_cvt(x, ah[rt][kt], al[rt][kt]);
    }
  f32x4 oacc[2][8];
#pragma unroll
  for (int mt = 0; mt < 2; ++mt)
#pragma unroll
    for (int nt = 0; nt < 8; ++nt) oacc[mt][nt] = z4();
  float M0 = -1e30f, M1 = -1e30f, L0 = 0.f, L1 = 0.f;
  u32* vTw = &vT[w][0];
#pragma unroll 1
  for (int kb = 0; kb < NKB; ++kb) {
    const int kv0 = kb * KVB;
    f32x4 st[2][2];
#pragma unroll
    for (int ct = 0; ct < 2; ++ct)
#pragma unroll
      for (int rt = 0; rt < 2; ++rt) st[ct][rt] = z4();
#pragma unroll
    for (int kt = 0; kt < 4; ++kt) {
      FbFrag qh[2], ql[2];
#pragma unroll
      for (int kvt = 0; kvt < 2; ++kvt) {
        const float* src = Qb + (size_t)(kv0 + kvt * 16 + m) * DD + dw + kt * 32 + g * 8;
        f32x4 v0 = ((const f32x4*)src)[0], v1 = ((const f32x4*)src)[1];
        float x[8];
#pragma unroll
        for (int i = 0; i < 4; ++i) { x[i] = v0[i]; x[4 + i] = v1[i]; }
        fb_cvt(x, qh[kvt], ql[kvt]);
      }
      const int dbase = kt * 32 + g * 8;
#pragma unroll
      for (int i = 0; i < 4; ++i) {
        u32 we = (qh[1].u[i] << 16) | (qh[0].u[i] & 0xffffu);
        u32 wo = (qh[1].u[i] & 0xffff0000u) | (qh[0].u[i] >> 16);
        vTw[(dbase + 2 * i) * FB_VSTR + m] = we;
        vTw[(dbase + 2 * i + 1) * FB_VSTR + m] = wo;
      }
#pragma unroll
      for (int ct = 0; ct < 2; ++ct)
#pragma unroll
        for (int rt = 0; rt < 2; ++rt) {
          st[ct][rt] = __builtin_amdgcn_mfma_f32_16x16x32_bf16(qh[ct].v, ah[rt][kt].v, st[ct][rt], 0, 0, 0);
          st[ct][rt] = __builtin_amdgcn_mfma_f32_16x16x32_bf16(qh[ct].v, al[rt][kt].v, st[ct][rt], 0, 0, 0);
          st[ct][rt] = __builtin_amdgcn_mfma_f32_16x16x32_bf16(ql[ct].v, ah[rt][kt].v, st[ct][rt], 0, 0, 0);
        }
    }
#pragma unroll
    for (int ct = 0; ct < 2; ++ct)
#pragma unroll
      for (int rt = 0; rt < 2; ++rt)
        *(f32x4*)&sp[w][rt * 16 + m][ct * 16 + g * 4] = st[ct][rt];
    __syncthreads();
#pragma unroll
    for (int rep = 0; rep < 2; ++rep) {
      const int pp = tid + rep * 512;
      const int r = pp >> 5, c = pp & 31;
      float acc = 0.f;
#pragma unroll
      for (int ww = 0; ww < 8; ++ww) acc += sp[ww][r][c];
      ssum[r][c] = acc;
    }
    __syncthreads();
    f32x4 sv[2][2];
#pragma unroll
    for (int ct = 0; ct < 2; ++ct)
#pragma unroll
      for (int rt = 0; rt < 2; ++rt)
        sv[ct][rt] = *(const f32x4*)&ssum[rt * 16 + m][ct * 16 + g * 4];
    float mx0 = -1e30f, mx1 = -1e30f;
#pragma unroll
    for (int ct = 0; ct < 2; ++ct)
#pragma unroll
      for (int j = 0; j < 4; ++j) {
        mx0 = fmaxf(mx0, sv[ct][0][j]);
        mx1 = fmaxf(mx1, sv[ct][1][j]);
      }
    mx0 = fmaxf(mx0, __shfl_xor(mx0, 16));
    mx0 = fmaxf(mx0, __shfl_xor(mx0, 32));
    mx1 = fmaxf(mx1, __shfl_xor(mx1, 16));
    mx1 = fmaxf(mx1, __shfl_xor(mx1, 32));
    if (__any((mx0 > M0) | (mx1 > M1))) {
      const float nM0 = fmaxf(M0, mx0), nM1 = fmaxf(M1, mx1);
      const float c0 = __expf(M0 - nM0), c1 = __expf(M1 - nM1);
      M0 = nM0; M1 = nM1; L0 *= c0; L1 *= c1;
      f32x4 cr0, cr1;
#pragma unroll
      for (int j = 0; j < 4; ++j) { cr0[j] = __shfl(c0, g * 4 + j); cr1[j] = __shfl(c1, g * 4 + j); }
#pragma unroll
      for (int nt = 0; nt < 8; ++nt)
#pragma unroll
        for (int j = 0; j < 4; ++j) { oacc[0][nt][j] *= cr0[j]; oacc[1][nt][j] *= cr1[j]; }
    }
    f32x4 p00, p10, p01, p11;
#pragma unroll
    for (int j = 0; j < 4; ++j) {
      p00[j] = __expf(sv[0][0][j] - M0);
      p10[j] = __expf(sv[1][0][j] - M0);
      p01[j] = __expf(sv[0][1][j] - M1);
      p11[j] = __expf(sv[1][1][j] - M1);
    }
    float rs0 = 0.f, rs1 = 0.f;
#pragma unroll
    for (int j = 0; j < 4; ++j) { rs0 += p00[j] + p10[j]; rs1 += p01[j] + p11[j]; }
    rs0 += __shfl_xor(rs0, 16); rs0 += __shfl_xor(rs0, 32);
    rs1 += __shfl_xor(rs1, 16); rs1 += __shfl_xor(rs1, 32);
    L0 += rs0; L1 += rs1;
    FbFrag pa0, pa1;
#pragma unroll
    for (int j = 0; j < 4; ++j) {
      pa0.u[j] = fb_pack(p00[j], p10[j]);
      pa1.u[j] = fb_pack(p01[j], p11[j]);
    }
#pragma unroll
    for (int nt = 0; nt < 8; ++nt) {
      const u32* src = &vTw[(nt * 16 + m) * FB_VSTR + g * 4];
      FbFrag bq;
      *(u32x2_t*)&bq.u[0] = *(const u32x2_t*)&src[0];
      *(u32x2_t*)&bq.u[2] = *(const u32x2_t*)&src[2];
      oacc[0][nt] = __builtin_amdgcn_mfma_f32_16x16x32_bf16(pa0.v, bq.v, oacc[0][nt], 0, 0, 0);
      oacc[1][nt] = __builtin_amdgcn_mfma_f32_16x16x32_bf16(pa1.v, bq.v, oacc[1][nt], 0, 0, 0);
    }
  }
  f32x4 i0, i1;
#pragma unroll
  for (int j = 0; j < 4; ++j) {
    i0[j] = 1.f / __shfl(L0, g * 4 + j);
    i1[j] = 1.f / __shfl(L1, g * 4 + j);
  }
#pragma unroll
  for (int mt = 0; mt < 2; ++mt)
#pragma unroll
    for (int nt = 0; nt < 8; ++nt)
#pragma unroll
      for (int j = 0; j < 4; ++j) {
        const int r = mt * 16 + g * 4 + j;
        const int dc = dw + nt * 16 + m;
        Ob[(size_t)r * DD + dc] = oacc[mt][nt][j] * (mt ? i1[j] : i0[j]);
      }
}

extern "C" void kernel_launch(void* const* d_in, const int* in_sizes, int n_in,
                              void* d_out, int out_size, void* d_ws, size_t ws_size,
                              hipStream_t stream) {
  const float* q = (const float*)d_in[0];
  const float* a = (const float*)d_in[1];
  float* o = (float*)d_out;
  if (ws_size >= WS_NEED) {
    char* ws = (char*)d_ws;
    u16* qh  = (u16*)(ws + WS_QH);
    u32* qti = (u32*)(ws + WS_QTI);
    prepass<<<NB * 64 * 16, 256, 0, stream>>>(q, qh, qti);
    attn_main<<<NB * (SEQ / BM), 512, 0, stream>>>(a, qh, qti, o);
  } else {
    attn_fb<<<NB * (SEQ / 32), 512, 0, stream>>>(q, a, o);
  }
  (void)in_sizes; (void)n_in; (void)out_size;
}

// Round 7
// 761.613 us; speedup vs baseline: 4.0367x; 1.4202x over previous
//
#include <hip/hip_runtime.h>
#include <stdint.h>

typedef short bf16x8 __attribute__((ext_vector_type(8)));
typedef _Float16 f16x8 __attribute__((ext_vector_type(8)));
typedef float f32x4 __attribute__((ext_vector_type(4)));
typedef unsigned int u32x2_t __attribute__((ext_vector_type(2)));
typedef unsigned int u32x4_t __attribute__((ext_vector_type(4)));
typedef unsigned int u32;
typedef unsigned short u16;
typedef unsigned char u8;
typedef unsigned long long u64;

#define NB  16
#define SEQ 2048
#define DD  1024
#define BM  32     // a-rows per WG
#define KVB 32
#define NWAVE 8
#define NKB (SEQ / KVB)

// d_ws layout (bytes):
//   QH  [b][kv][d] f16 (round-to-nearest)                    : 64 MB
//   QT2 [b][kb][d][16 u32] kv-pair-interleaved f16 Q^T tiles : 64 MB
#define WS_QH  0ULL
#define WS_QT2 (64ULL << 20)
#define WS_NEED (128ULL << 20)

union HF { u32 u[4]; u32x4_t u4; f16x8 v; };

__device__ __forceinline__ f32x4 z4() {
  f32x4 v; v[0] = 0.f; v[1] = 0.f; v[2] = 0.f; v[3] = 0.f; return v;
}
__device__ __forceinline__ float h16(float x) {
  // round-to-nearest f16-representable value, kept in f32
  return __uint_as_float((__float_as_uint(x) + 0x1000u) & 0xFFFFE000u);
}
__device__ __forceinline__ u32 packh(float a, float b) {
  auto t = __builtin_amdgcn_cvt_pkrtz(a, b);   // exact when inputs f16-representable
  return *(u32*)&t;
}
__device__ __forceinline__ f32x4 mfma16(f16x8 a, f16x8 b, f32x4 c) {
  return __builtin_amdgcn_mfma_f32_16x16x32_f16(a, b, c, 0, 0, 0);
}
// Raw barrier: LDS-ordering only (lgkmcnt), leaves VMEM loads in flight (no vmcnt drain).
__device__ __forceinline__ void wg_barrier() {
  asm volatile("s_waitcnt lgkmcnt(0)" ::: "memory");
  __builtin_amdgcn_s_barrier();
  asm volatile("" ::: "memory");
}

// ---------------- prepass: q -> QH (f16 rows) + QT2 (kb-blocked transposed) ----------------
__global__ __launch_bounds__(256)
void prepass(const float* __restrict__ Q, u16* __restrict__ QH, u32* __restrict__ QT2) {
  __shared__ u16 hl[32][72];
  const int t = threadIdx.x;
  const int bidx = (int)blockIdx.x;          // b*1024 + kvb*16 + db
  const int db = bidx & 15, kvb = (bidx >> 4) & 63, b = bidx >> 10;
  const int r = t >> 3, dc = (t & 7) * 8;
  const int kv = kvb * 32 + r;
  const size_t row = (size_t)(b * SEQ + kv) * DD + db * 64 + dc;
  f32x4 v0 = ((const f32x4*)(Q + row))[0];
  f32x4 v1 = ((const f32x4*)(Q + row))[1];
  float e[8] = { v0[0], v0[1], v0[2], v0[3], v1[0], v1[1], v1[2], v1[3] };
  u32x4_t hw;
#pragma unroll
  for (int j = 0; j < 4; ++j)
    hw[j] = packh(h16(e[2 * j]), h16(e[2 * j + 1]));
  *(u32x4_t*)(QH + row) = hw;
  // QT2 staging (f16, transposed, (kv, kv+16) pair-interleaved per kb block)
#pragma unroll
  for (int j = 0; j < 4; ++j) {
    hl[r][dc + 2 * j]     = (u16)(hw[j] & 0xffffu);
    hl[r][dc + 2 * j + 1] = (u16)(hw[j] >> 16);
  }
  __syncthreads();
  const int d = t >> 2, i4 = (t & 3) * 4;
  u32x4_t w;
#pragma unroll
  for (int ii = 0; ii < 4; ++ii) {
    const int i = i4 + ii;
    w[ii] = (u32)hl[i][d] | ((u32)hl[i + 16][d] << 16);  // (kv0+i, kv0+16+i)
  }
  // QT2[b][kvb][db*64+d][i4..i4+3]
  u32* dst = QT2 + (((size_t)(b * 64 + kvb) * 1024) + (db * 64 + d)) * 16 + i4;
  *(u32x4_t*)dst = w;
}

// ---------------- main fused kernel: 1-barrier pipelined, coalesced V ----------------
__global__ __launch_bounds__(512, 2)
void attn_main(const float* __restrict__ Ag, const u16* __restrict__ QH,
               const u32* __restrict__ QT2, float* __restrict__ Og) {
  __shared__ float sp[2][NWAVE][BM][36];   // double-buffered per-wave partial S^T (73728 B)
  __shared__ float ssum[2][BM][36];        // double-buffered reduced S^T          ( 9216 B)

  const int tid  = (int)threadIdx.x;
  const int w    = tid >> 6;
  const int lane = tid & 63;
  const int g    = lane >> 4;
  const int m    = lane & 15;
  const int dw   = w * 128;

  // XCD chunk swizzle: 1024 = 8 * 128 (bijective); one batch's WGs share an XCD
  const int p = (int)blockIdx.x;
  const int l = (p & 7) * 128 + (p >> 3);
  const int b = l >> 6;
  const int ablk = l & 63;

  const float* Abase = Ag + ((size_t)(b * SEQ + ablk * BM)) * DD;
  float*       Ob    = Og + ((size_t)(b * SEQ + ablk * BM)) * DD;
  const u16* Qb = QH + (size_t)(b * SEQ) * DD + dw + g * 8;        // + kv*DD + kt*32 at use
  const u32* Vb = QT2 + (size_t)(b * 64) * 16384 + (size_t)(dw + m) * 16 + g * 4;

  // ---- prologue: A-tile -> f16 fragments (regs only)
  f16x8 ah[2][4];
#pragma unroll
  for (int rt = 0; rt < 2; ++rt) {
#pragma unroll
    for (int kt = 0; kt < 4; ++kt) {
      const float* src = Abase + (size_t)(rt * 16 + m) * DD + dw + kt * 32 + g * 8;
      f32x4 v0 = ((const f32x4*)src)[0];
      f32x4 v1 = ((const f32x4*)src)[1];
      float e[8] = { v0[0], v0[1], v0[2], v0[3], v1[0], v1[1], v1[2], v1[3] };
      HF fh;
#pragma unroll
      for (int j = 0; j < 4; ++j) fh.u[j] = packh(h16(e[2 * j]), h16(e[2 * j + 1]));
      ah[rt][kt] = fh.v;
    }
  }

  f32x4 oacc[2][8];
#pragma unroll
  for (int mt = 0; mt < 2; ++mt)
#pragma unroll
    for (int nt = 0; nt < 8; ++nt) oacc[mt][nt] = z4();

  float M0 = -1e30f, M1 = -1e30f, L0 = 0.f, L1 = 0.f;

  // ---- pipeline prologue: S(0) -> sp[0]; q := Q(1)
  HF q[2][4];
#pragma unroll
  for (int ct = 0; ct < 2; ++ct)
#pragma unroll
    for (int kt = 0; kt < 4; ++kt)
      q[ct][kt].u4 = *(const u32x4_t*)(Qb + (size_t)(ct * 16 + m) * DD + kt * 32);
  {
    f32x4 st[2][2];
#pragma unroll
    for (int ct = 0; ct < 2; ++ct)
#pragma unroll
      for (int rt = 0; rt < 2; ++rt) st[ct][rt] = z4();
#pragma unroll
    for (int kt = 0; kt < 4; ++kt)
#pragma unroll
      for (int ct = 0; ct < 2; ++ct) {
        st[ct][0] = mfma16(q[ct][kt].v, ah[0][kt], st[ct][0]);
        st[ct][1] = mfma16(q[ct][kt].v, ah[1][kt], st[ct][1]);
      }
#pragma unroll
    for (int ct = 0; ct < 2; ++ct)
#pragma unroll
      for (int rt = 0; rt < 2; ++rt)
        *(f32x4*)&sp[0][w][rt * 16 + m][ct * 16 + g * 4] = st[ct][rt];
  }
#pragma unroll
  for (int ct = 0; ct < 2; ++ct)
#pragma unroll
    for (int kt = 0; kt < 4; ++kt)
      q[ct][kt].u4 = *(const u32x4_t*)(Qb + (size_t)(KVB + ct * 16 + m) * DD + kt * 32);
  wg_barrier();

#pragma unroll 1
  for (int kb = 0; kb < NKB; ++kb) {
    const int A = kb & 1, B = A ^ 1;

    // ---- (1) V fragments for PV(kb): one contiguous 1KB load per nt, in flight until PV
    const u32* vrow = Vb + (size_t)kb * 16384;
    u32x4_t bq[8];
#pragma unroll
    for (int nt = 0; nt < 8; ++nt)
      bq[nt] = *(const u32x4_t*)(vrow + nt * 256);

    // ---- (2) cross-wave reduce of sp[A] -> ssum[A] (overlaps with (3))
#pragma unroll
    for (int rep = 0; rep < 2; ++rep) {
      const int pp = tid + rep * 512;
      const int r = pp >> 5, c = pp & 31;
      float acc = sp[A][0][r][c];
#pragma unroll
      for (int ww = 1; ww < NWAVE; ++ww) acc += sp[A][ww][r][c];
      ssum[A][r][c] = acc;
    }

    // ---- (3) S(kb+1) -> sp[B]; then (4) prefetch Q(kb+2)
    if (kb + 1 < NKB) {
      f32x4 st[2][2];
#pragma unroll
      for (int ct = 0; ct < 2; ++ct)
#pragma unroll
        for (int rt = 0; rt < 2; ++rt) st[ct][rt] = z4();
#pragma unroll
      for (int kt = 0; kt < 4; ++kt)
#pragma unroll
        for (int ct = 0; ct < 2; ++ct) {
          st[ct][0] = mfma16(q[ct][kt].v, ah[0][kt], st[ct][0]);
          st[ct][1] = mfma16(q[ct][kt].v, ah[1][kt], st[ct][1]);
        }
#pragma unroll
      for (int ct = 0; ct < 2; ++ct)
#pragma unroll
        for (int rt = 0; rt < 2; ++rt)
          *(f32x4*)&sp[B][w][rt * 16 + m][ct * 16 + g * 4] = st[ct][rt];
      if (kb + 2 < NKB) {
        const int kvn = (kb + 2) * KVB;
#pragma unroll
        for (int ct = 0; ct < 2; ++ct)
#pragma unroll
          for (int kt = 0; kt < 4; ++kt)
            q[ct][kt].u4 = *(const u32x4_t*)(Qb + (size_t)(kvn + ct * 16 + m) * DD + kt * 32);
      }
    }

    // ---- (5) single barrier: LDS-order only; q/bq loads stay in flight
    wg_barrier();

    // ---- (6) softmax from ssum[A] (redundant per wave); PV(kb)
    f32x4 sv[2][2];
#pragma unroll
    for (int ct = 0; ct < 2; ++ct)
#pragma unroll
      for (int rt = 0; rt < 2; ++rt)
        sv[ct][rt] = *(const f32x4*)&ssum[A][rt * 16 + m][ct * 16 + g * 4];

    float mx0 = -1e30f, mx1 = -1e30f;
#pragma unroll
    for (int ct = 0; ct < 2; ++ct)
#pragma unroll
      for (int j = 0; j < 4; ++j) {
        mx0 = fmaxf(mx0, sv[ct][0][j]);
        mx1 = fmaxf(mx1, sv[ct][1][j]);
      }
    mx0 = fmaxf(mx0, __shfl_xor(mx0, 16));
    mx0 = fmaxf(mx0, __shfl_xor(mx0, 32));
    mx1 = fmaxf(mx1, __shfl_xor(mx1, 16));
    mx1 = fmaxf(mx1, __shfl_xor(mx1, 32));

    if (__any((mx0 > M0) | (mx1 > M1))) {
      const float nM0 = fmaxf(M0, mx0), nM1 = fmaxf(M1, mx1);
      const float c0 = __expf(M0 - nM0), c1 = __expf(M1 - nM1);
      M0 = nM0; M1 = nM1;
      L0 *= c0; L1 *= c1;
      f32x4 cr0, cr1;
#pragma unroll
      for (int j = 0; j < 4; ++j) {
        cr0[j] = __shfl(c0, g * 4 + j);
        cr1[j] = __shfl(c1, g * 4 + j);
      }
#pragma unroll
      for (int nt = 0; nt < 8; ++nt)
#pragma unroll
        for (int j = 0; j < 4; ++j) {
          oacc[0][nt][j] *= cr0[j];
          oacc[1][nt][j] *= cr1[j];
        }
    }

    f32x4 p00, p10, p01, p11;   // [ct][row-half]
#pragma unroll
    for (int j = 0; j < 4; ++j) {
      p00[j] = __expf(sv[0][0][j] - M0);
      p10[j] = __expf(sv[1][0][j] - M0);
      p01[j] = __expf(sv[0][1][j] - M1);
      p11[j] = __expf(sv[1][1][j] - M1);
    }
    float rs0 = 0.f, rs1 = 0.f;
#pragma unroll
    for (int j = 0; j < 4; ++j) {
      rs0 += p00[j] + p10[j];
      rs1 += p01[j] + p11[j];
    }
    rs0 += __shfl_xor(rs0, 16); rs0 += __shfl_xor(rs0, 32);
    rs1 += __shfl_xor(rs1, 16); rs1 += __shfl_xor(rs1, 32);
    L0 += rs0; L1 += rs1;

    HF pa0, pa1;  // u[j]: lo=kv0+g*4+j, hi=kv0+16+g*4+j (matches QT2 words)
#pragma unroll
    for (int j = 0; j < 4; ++j) {
      pa0.u[j] = packh(p00[j], p10[j]);
      pa1.u[j] = packh(p01[j], p11[j]);
    }

#pragma unroll
    for (int nt = 0; nt < 8; ++nt) {
      HF bqv; bqv.u4 = bq[nt];
      oacc[0][nt] = mfma16(pa0.v, bqv.v, oacc[0][nt]);
      oacc[1][nt] = mfma16(pa1.v, bqv.v, oacc[1][nt]);
    }
  }

  // ---- epilogue: normalize by L and store
  f32x4 i0, i1;
#pragma unroll
  for (int j = 0; j < 4; ++j) {
    i0[j] = 1.f / __shfl(L0, g * 4 + j);
    i1[j] = 1.f / __shfl(L1, g * 4 + j);
  }
#pragma unroll
  for (int mt = 0; mt < 2; ++mt)
#pragma unroll
    for (int nt = 0; nt < 8; ++nt)
#pragma unroll
      for (int j = 0; j < 4; ++j) {
        const int r  = mt * 16 + g * 4 + j;
        const int dc = dw + nt * 16 + m;
        Ob[(size_t)r * DD + dc] = oacc[mt][nt][j] * (mt ? i1[j] : i0[j]);
      }
}

// ---------------- fallback (round-2 kernel, proven) ----------------
#define FB_VSTR 18
__device__ __forceinline__ u32 fb_rn16(u32 bb) { return (bb + 0x8000u) & 0xffff0000u; }
__device__ __forceinline__ u32 fb_pack(float x0, float x1) {
  return fb_rn16(__float_as_uint(x1)) | (fb_rn16(__float_as_uint(x0)) >> 16);
}
union FbFrag { u32 u[4]; u32x4_t u4; bf16x8 v; };
__device__ __forceinline__ void fb_cvt(const float* x, FbFrag& fh, FbFrag& fl) {
#pragma unroll
  for (int i = 0; i < 4; ++i) {
    float x0 = x[2 * i], x1 = x[2 * i + 1];
    u32 h0 = fb_rn16(__float_as_uint(x0));
    u32 h1 = fb_rn16(__float_as_uint(x1));
    fh.u[i] = h1 | (h0 >> 16);
    fl.u[i] = fb_pack(x0 - __uint_as_float(h0), x1 - __uint_as_float(h1));
  }
}

__global__ __launch_bounds__(512, 2)
void attn_fb(const float* __restrict__ Qg, const float* __restrict__ Ag,
             float* __restrict__ Og) {
  __shared__ u32 vT[8][128 * FB_VSTR];
  __shared__ float sp[8][32][36];
  __shared__ float ssum[32][36];
  const int tid = threadIdx.x, w = tid >> 6, lane = tid & 63, g = lane >> 4, m = lane & 15;
  const int bid = (int)blockIdx.x, b = bid >> 6, ablk = bid & 63, dw = w * 128;
  const float* Qb = Qg + (size_t)b * SEQ * DD;
  const float* Abase = Ag + ((size_t)b * SEQ + ablk * 32) * DD;
  float* Ob = Og + ((size_t)b * SEQ + ablk * 32) * DD;
  FbFrag ah[2][4], al[2][4];
#pragma unroll
  for (int rt = 0; rt < 2; ++rt)
#pragma unroll
    for (int kt = 0; kt < 4; ++kt) {
      const float* src = Abase + (size_t)(rt * 16 + m) * DD + dw + kt * 32 + g * 8;
      f32x4 v0 = ((const f32x4*)src)[0], v1 = ((const f32x4*)src)[1];
      float x[8];
#pragma unroll
      for (int i = 0; i < 4; ++i) { x[i] = v0[i]; x[4 + i] = v1[i]; }
      fb_cvt(x, ah[rt][kt], al[rt][kt]);
    }
  f32x4 oacc[2][8];
#pragma unroll
  for (int mt = 0; mt < 2; ++mt)
#pragma unroll
    for (int nt = 0; nt < 8; ++nt) oacc[mt][nt] = z4();
  float M0 = -1e30f, M1 = -1e30f, L0 = 0.f, L1 = 0.f;
  u32* vTw = &vT[w][0];
#pragma unroll 1
  for (int kb = 0; kb < NKB; ++kb) {
    const int kv0 = kb * KVB;
    f32x4 st[2][2];
#pragma unroll
    for (int ct = 0; ct < 2; ++ct)
#pragma unroll
      for (int rt = 0; rt < 2; ++rt) st[ct][rt] = z4();
#pragma unroll
    for (int kt = 0; kt < 4; ++kt) {
      FbFrag qh[2], ql[2];
#pragma unroll
      for (int kvt = 0; kvt < 2; ++kvt) {
        const float* src = Qb + (size_t)(kv0 + kvt * 16 + m) * DD + dw + kt * 32 + g * 8;
        f32x4 v0 = ((const f32x4*)src)[0], v1 = ((const f32x4*)src)[1];
        float x[8];
#pragma unroll
        for (int i = 0; i < 4; ++i) { x[i] = v0[i]; x[4 + i] = v1[i]; }
        fb_cvt(x, qh[kvt], ql[kvt]);
      }
      const int dbase = kt * 32 + g * 8;
#pragma unroll
      for (int i = 0; i < 4; ++i) {
        u32 we = (qh[1].u[i] << 16) | (qh[0].u[i] & 0xffffu);
        u32 wo = (qh[1].u[i] & 0xffff0000u) | (qh[0].u[i] >> 16);
        vTw[(dbase + 2 * i) * FB_VSTR + m] = we;
        vTw[(dbase + 2 * i + 1) * FB_VSTR + m] = wo;
      }
#pragma unroll
      for (int ct = 0; ct < 2; ++ct)
#pragma unroll
        for (int rt = 0; rt < 2; ++rt) {
          st[ct][rt] = __builtin_amdgcn_mfma_f32_16x16x32_bf16(qh[ct].v, ah[rt][kt].v, st[ct][rt], 0, 0, 0);
          st[ct][rt] = __builtin_amdgcn_mfma_f32_16x16x32_bf16(qh[ct].v, al[rt][kt].v, st[ct][rt], 0, 0, 0);
          st[ct][rt] = __builtin_amdgcn_mfma_f32_16x16x32_bf16(ql[ct].v, ah[rt][kt].v, st[ct][rt], 0, 0, 0);
        }
    }
#pragma unroll
    for (int ct = 0; ct < 2; ++ct)
#pragma unroll
      for (int rt = 0; rt < 2; ++rt)
        *(f32x4*)&sp[w][rt * 16 + m][ct * 16 + g * 4] = st[ct][rt];
    __syncthreads();
#pragma unroll
    for (int rep = 0; rep < 2; ++rep) {
      const int pp = tid + rep * 512;
      const int r = pp >> 5, c = pp & 31;
      float acc = 0.f;
#pragma unroll
      for (int ww = 0; ww < 8; ++ww) acc += sp[ww][r][c];
      ssum[r][c] = acc;
    }
    __syncthreads();
    f32x4 sv[2][2];
#pragma unroll
    for (int ct = 0; ct < 2; ++ct)
#pragma unroll
      for (int rt = 0; rt < 2; ++rt)
        sv[ct][rt] = *(const f32x4*)&ssum[rt * 16 + m][ct * 16 + g * 4];
    float mx0 = -1e30f, mx1 = -1e30f;
#pragma unroll
    for (int ct = 0; ct < 2; ++ct)
#pragma unroll
      for (int j = 0; j < 4; ++j) {
        mx0 = fmaxf(mx0, sv[ct][0][j]);
        mx1 = fmaxf(mx1, sv[ct][1][j]);
      }
    mx0 = fmaxf(mx0, __shfl_xor(mx0, 16));
    mx0 = fmaxf(mx0, __shfl_xor(mx0, 32));
    mx1 = fmaxf(mx1, __shfl_xor(mx1, 16));
    mx1 = fmaxf(mx1, __shfl_xor(mx1, 32));
    if (__any((mx0 > M0) | (mx1 > M1))) {
      const float nM0 = fmaxf(M0, mx0), nM1 = fmaxf(M1, mx1);
      const float c0 = __expf(M0 - nM0), c1 = __expf(M1 - nM1);
      M0 = nM0; M1 = nM1; L0 *= c0; L1 *= c1;
      f32x4 cr0, cr1;
#pragma unroll
      for (int j = 0; j < 4; ++j) { cr0[j] = __shfl(c0, g * 4 + j); cr1[j] = __shfl(c1, g * 4 + j); }
#pragma unroll
      for (int nt = 0; nt < 8; ++nt)
#pragma unroll
        for (int j = 0; j < 4; ++j) { oacc[0][nt][j] *= cr0[j]; oacc[1][nt][j] *= cr1[j]; }
    }
    f32x4 p00, p10, p01, p11;
#pragma unroll
    for (int j = 0; j < 4; ++j) {
      p00[j] = __expf(sv[0][0][j] - M0);
      p10[j] = __expf(sv[1][0][j] - M0);
      p01[j] = __expf(sv[0][1][j] - M1);
      p11[j] = __expf(sv[1][1][j] - M1);
    }
    float rs0 = 0.f, rs1 = 0.f;
#pragma unroll
    for (int j = 0; j < 4; ++j) { rs0 += p00[j] + p10[j]; rs1 += p01[j] + p11[j]; }
    rs0 += __shfl_xor(rs0, 16); rs0 += __shfl_xor(rs0, 32);
    rs1 += __shfl_xor(rs1, 16); rs1 += __shfl_xor(rs1, 32);
    L0 += rs0; L1 += rs1;
    FbFrag pa0, pa1;
#pragma unroll
    for (int j = 0; j < 4; ++j) {
      pa0.u[j] = fb_pack(p00[j], p10[j]);
      pa1.u[j] = fb_pack(p01[j], p11[j]);
    }
#pragma unroll
    for (int nt = 0; nt < 8; ++nt) {
      const u32* src = &vTw[(nt * 16 + m) * FB_VSTR + g * 4];
      FbFrag bq;
      *(u32x2_t*)&bq.u[0] = *(const u32x2_t*)&src[0];
      *(u32x2_t*)&bq.u[2] = *(const u32x2_t*)&src[2];
      oacc[0][nt] = __builtin_amdgcn_mfma_f32_16x16x32_bf16(pa0.v, bq.v, oacc[0][nt], 0, 0, 0);
      oacc[1][nt] = __builtin_amdgcn_mfma_f32_16x16x32_bf16(pa1.v, bq.v, oacc[1][nt], 0, 0, 0);
    }
  }
  f32x4 i0, i1;
#pragma unroll
  for (int j = 0; j < 4; ++j) {
    i0[j] = 1.f / __shfl(L0, g * 4 + j);
    i1[j] = 1.f / __shfl(L1, g * 4 + j);
  }
#pragma unroll
  for (int mt = 0; mt < 2; ++mt)
#pragma unroll
    for (int nt = 0; nt < 8; ++nt)
#pragma unroll
      for (int j = 0; j < 4; ++j) {
        const int r = mt * 16 + g * 4 + j;
        const int dc = dw + nt * 16 + m;
        Ob[(size_t)r * DD + dc] = oacc[mt][nt][j] * (mt ? i1[j] : i0[j]);
      }
}

extern "C" void kernel_launch(void* const* d_in, const int* in_sizes, int n_in,
                              void* d_out, int out_size, void* d_ws, size_t ws_size,
                              hipStream_t stream) {
  const float* q = (const float*)d_in[0];
  const float* a = (const float*)d_in[1];
  float* o = (float*)d_out;
  if (ws_size >= WS_NEED) {
    char* ws = (char*)d_ws;
    u16* qh  = (u16*)(ws + WS_QH);
    u32* qt2 = (u32*)(ws + WS_QT2);
    prepass<<<NB * 64 * 16, 256, 0, stream>>>(q, qh, qt2);
    attn_main<<<NB * (SEQ / BM), 512, 0, stream>>>(a, qh, qt2, o);
  } else {
    attn_fb<<<NB * (SEQ / 32), 512, 0, stream>>>(q, a, o);
  }
  (void)in_sizes; (void)n_in; (void)out_size;
}